// Round 3
// baseline (216.709 us; speedup 1.0000x reference)
//
#include <hip/hip_runtime.h>
#include <hip/hip_bf16.h>

// Combine: out[b,:] = branches[argmax(gate[b,:4])][b,:]
// B=4096 rows, D=4096 fp32 per row, N=4 branches.
// Memory-bound select-copy. R3: native ext_vector float4 so the nontemporal
// builtin compiles; 4 loads issued back-to-back for 4-deep vmcnt ILP.

#define B 4096
#define D 4096

typedef float fvec4 __attribute__((ext_vector_type(4)));

__global__ __launch_bounds__(256) void combine_kernel(
    const float* __restrict__ b0, const float* __restrict__ b1,
    const float* __restrict__ b2, const float* __restrict__ b3,
    const float* __restrict__ gate, float* __restrict__ out) {

    const int row = blockIdx.x;

    // Gate row: one 16B load, L1-broadcast across the block.
    fvec4 g = ((const fvec4*)gate)[row];

    // First-occurrence argmax (strict > matches jnp.argmax tie-break).
    int idx = 0;
    float best = g.x;
    if (g.y > best) { best = g.y; idx = 1; }
    if (g.z > best) { best = g.z; idx = 2; }
    if (g.w > best) { best = g.w; idx = 3; }

    // Block-uniform branch select — no divergence.
    const float* src = (idx == 0) ? b0 : (idx == 1) ? b1 : (idx == 2) ? b2 : b3;

    const fvec4* s = (const fvec4*)(src + (size_t)row * D);
    fvec4*       d = (fvec4*)(out + (size_t)row * D);

    const int t = threadIdx.x;

    // Issue all 4 vector loads back-to-back (4 outstanding vmcnt),
    // then drain into 4 nontemporal stores.
    fvec4 v0 = s[t];
    fvec4 v1 = s[t + 256];
    fvec4 v2 = s[t + 512];
    fvec4 v3 = s[t + 768];

    __builtin_nontemporal_store(v0, &d[t]);
    __builtin_nontemporal_store(v1, &d[t + 256]);
    __builtin_nontemporal_store(v2, &d[t + 512]);
    __builtin_nontemporal_store(v3, &d[t + 768]);
}

extern "C" void kernel_launch(void* const* d_in, const int* in_sizes, int n_in,
                              void* d_out, int out_size, void* d_ws, size_t ws_size,
                              hipStream_t stream) {
    const float* b0   = (const float*)d_in[0];
    const float* b1   = (const float*)d_in[1];
    const float* b2   = (const float*)d_in[2];
    const float* b3   = (const float*)d_in[3];
    const float* gate = (const float*)d_in[4];
    float* out = (float*)d_out;

    combine_kernel<<<B, 256, 0, stream>>>(b0, b1, b2, b3, gate, out);
}